// Round 1
// baseline (1033.323 us; speedup 1.0000x reference)
//
#include <hip/hip_runtime.h>
#include <math.h>

#define QDIM 256
#define KDIM 512
#define NB   1024        // blocks in main streaming kernel
#define TPB  256         // threads per block
#define WPB  (TPB / 64)  // waves per block = 4

// ---------------------------------------------------------------------------
// Kernel 1: q = W @ query + b.  W is [KDIM, QDIM] row-major.
// Wave-per-row: lane l loads W4[row*64 + l] (float4) and query4[l].
// 32 waves total (8 blocks x 256), 16 rows per wave.
// ---------------------------------------------------------------------------
__global__ __launch_bounds__(256) void qproj_kernel(const float* __restrict__ query,
                                                    const float* __restrict__ W,
                                                    const float* __restrict__ b,
                                                    float* __restrict__ q_out) {
    const int lane = threadIdx.x & 63;
    const int gw = (blockIdx.x * blockDim.x + threadIdx.x) >> 6;  // global wave 0..31
    const float4* W4 = (const float4*)W;
    const float4* q4 = (const float4*)query;
    float4 qv = q4[lane];  // query[lane*4 .. lane*4+3]
    const int row0 = gw * 16;
    for (int r = 0; r < 16; ++r) {
        const int row = row0 + r;
        float4 wv = W4[row * (QDIM / 4) + lane];
        float s = wv.x * qv.x + wv.y * qv.y + wv.z * qv.z + wv.w * qv.w;
#pragma unroll
        for (int i = 32; i >= 1; i >>= 1) s += __shfl_xor(s, i, 64);
        if (lane == 0) q_out[row] = s + b[row];
    }
}

// ---------------------------------------------------------------------------
// Kernel 2: streaming online-softmax over key/value rows.
// One wave handles 64 contiguous rows. Lane l holds q[l*4..] and q[256+l*4..]
// in registers; acc[512] is distributed 8 floats/lane. Per row:
// coalesced float4 loads (lanes cover bytes 0..1023 then 1024..2047 of the
// row), butterfly dot-reduce, wave-uniform online-softmax update.
// Block combines its 4 wave-partials via LDS -> one partial per block.
// ---------------------------------------------------------------------------
__global__ __launch_bounds__(TPB) void attn_partial_kernel(
    const float* __restrict__ key, const float* __restrict__ value,
    const float* __restrict__ q, float* __restrict__ pm, float* __restrict__ pl,
    float* __restrict__ pacc, int N) {
    const int lane = threadIdx.x & 63;
    const int w = threadIdx.x >> 6;
    const int gw = blockIdx.x * WPB + w;
    const int total_waves = NB * WPB;
    const int rpw = (N + total_waves - 1) / total_waves;  // 64

    const float4* key4 = (const float4*)key;
    const float4* val4 = (const float4*)value;
    const float4* q4 = (const float4*)q;

    const float4 qa = q4[lane];
    const float4 qb = q4[64 + lane];

    float m = -INFINITY;
    float lsum = 0.0f;
    float4 acca = {0.f, 0.f, 0.f, 0.f};
    float4 accb = {0.f, 0.f, 0.f, 0.f};

    const long row0 = (long)gw * rpw;
    for (int r = 0; r < rpw; ++r) {
        const long row = row0 + r;
        if (row >= N) break;
        const long base = row * (KDIM / 4);  // 128 float4 per row
        float4 ka = key4[base + lane];
        float4 kb = key4[base + 64 + lane];
        float s = ka.x * qa.x + ka.y * qa.y + ka.z * qa.z + ka.w * qa.w +
                  kb.x * qb.x + kb.y * qb.y + kb.z * qb.z + kb.w * qb.w;
#pragma unroll
        for (int i = 32; i >= 1; i >>= 1) s += __shfl_xor(s, i, 64);
        float4 va = val4[base + lane];
        float4 vb = val4[base + 64 + lane];
        if (s <= m) {  // common path: no rescale (wave-uniform branch)
            const float e = __expf(s - m);
            lsum += e;
            acca.x += e * va.x; acca.y += e * va.y; acca.z += e * va.z; acca.w += e * va.w;
            accb.x += e * vb.x; accb.y += e * vb.y; accb.z += e * vb.z; accb.w += e * vb.w;
        } else {       // new max: rescale (fires ~log N times per wave)
            const float scale = __expf(m - s);
            lsum = lsum * scale + 1.0f;
            acca.x = acca.x * scale + va.x; acca.y = acca.y * scale + va.y;
            acca.z = acca.z * scale + va.z; acca.w = acca.w * scale + va.w;
            accb.x = accb.x * scale + vb.x; accb.y = accb.y * scale + vb.y;
            accb.z = accb.z * scale + vb.z; accb.w = accb.w * scale + vb.w;
            m = s;
        }
    }

    // ---- block combine: 4 wave partials -> 1 block partial ----
    __shared__ float4 s_acc4[WPB][128];  // [wave][512 floats] = 8 KB
    __shared__ float s_m[WPB], s_l[WPB];
    s_acc4[w][lane] = acca;
    s_acc4[w][64 + lane] = accb;
    if (lane == 0) { s_m[w] = m; s_l[w] = lsum; }
    __syncthreads();

    float mblk = fmaxf(fmaxf(s_m[0], s_m[1]), fmaxf(s_m[2], s_m[3]));
    float wgt[WPB];
    float lblk = 0.0f;
#pragma unroll
    for (int i = 0; i < WPB; ++i) {
        wgt[i] = __expf(s_m[i] - mblk);
        lblk += s_l[i] * wgt[i];
    }
    const float* s_accf = (const float*)s_acc4;
    const int t = threadIdx.x;
#pragma unroll
    for (int jj = 0; jj < 2; ++jj) {
        const int j = t + jj * 256;
        float v = 0.0f;
#pragma unroll
        for (int i = 0; i < WPB; ++i) v += s_accf[i * 512 + j] * wgt[i];
        pacc[(long)blockIdx.x * 512 + j] = v;
    }
    if (t == 0) { pm[blockIdx.x] = mblk; pl[blockIdx.x] = lblk; }
}

// ---------------------------------------------------------------------------
// Kernel 3: combine NB=1024 block partials -> out[512].
// One block of 1024 threads.
// ---------------------------------------------------------------------------
__global__ __launch_bounds__(1024) void attn_final_kernel(
    const float* __restrict__ pm, const float* __restrict__ pl,
    const float* __restrict__ pacc, float* __restrict__ out) {
    __shared__ float s_w[NB];
    __shared__ float s_red[16];
    __shared__ float s_gm, s_gl;
    const int t = threadIdx.x;
    const int lane = t & 63;
    const int wid = t >> 6;  // 16 waves

    // global max of partial m's
    const float m = pm[t];
    float mm = m;
#pragma unroll
    for (int i = 32; i >= 1; i >>= 1) mm = fmaxf(mm, __shfl_xor(mm, i, 64));
    if (lane == 0) s_red[wid] = mm;
    __syncthreads();
    if (t == 0) {
        float g = s_red[0];
        for (int i = 1; i < 16; ++i) g = fmaxf(g, s_red[i]);
        s_gm = g;
    }
    __syncthreads();
    const float mg = s_gm;

    // per-partial weight + global denominator
    const float wv = __expf(m - mg);
    s_w[t] = wv;
    float lw = pl[t] * wv;
#pragma unroll
    for (int i = 32; i >= 1; i >>= 1) lw += __shfl_xor(lw, i, 64);
    __syncthreads();  // protect s_red reuse
    if (lane == 0) s_red[wid] = lw;
    __syncthreads();
    if (t == 0) {
        float L = 0.0f;
        for (int i = 0; i < 16; ++i) L += s_red[i];
        s_gl = L;
    }
    __syncthreads();
    const float L = s_gl;

    // weighted combine of acc partials (2 MB, L2-resident)
    if (t < 512) {
        float o = 0.0f;
        for (int bidx = 0; bidx < NB; ++bidx) {
            o += pacc[bidx * 512 + t] * s_w[bidx];
        }
        out[t] = o / L;
    }
}

extern "C" void kernel_launch(void* const* d_in, const int* in_sizes, int n_in,
                              void* d_out, int out_size, void* d_ws, size_t ws_size,
                              hipStream_t stream) {
    const float* query = (const float*)d_in[0];
    const float* key   = (const float*)d_in[1];
    const float* value = (const float*)d_in[2];
    const float* W     = (const float*)d_in[3];
    const float* b     = (const float*)d_in[4];
    float* out = (float*)d_out;
    const int N = in_sizes[1] / KDIM;

    float* ws   = (float*)d_ws;
    float* q    = ws;            // 512
    float* pm   = q + KDIM;      // NB
    float* pl   = pm + NB;       // NB
    float* pacc = pl + NB;       // NB * 512

    qproj_kernel<<<8, 256, 0, stream>>>(query, W, b, q);
    attn_partial_kernel<<<NB, TPB, 0, stream>>>(key, value, q, pm, pl, pacc, N);
    attn_final_kernel<<<1, 1024, 0, stream>>>(pm, pl, pacc, out);
}